// Round 1
// baseline (661.548 us; speedup 1.0000x reference)
//
#include <hip/hip_runtime.h>
#include <math.h>

#define HD 256
#define KD 16
#define SD 200
#define BD 512
#define TM 16   // rows per block in the MLP kernel

// ---------------------------------------------------------------------------
// Kernel 1: per-row 2-layer MLP + 256->16 logits + softmax over K + mask + /4.
// Writes P[b*S+s][k] (fp32) to workspace.
// ---------------------------------------------------------------------------
__global__ __launch_bounds__(256) void mlp_softk_kernel(
    const float* __restrict__ X, const int* __restrict__ mask,
    const float* __restrict__ W1, const float* __restrict__ b1,
    const float* __restrict__ W2, const float* __restrict__ b2,
    const float* __restrict__ W3, float* __restrict__ P)
{
    __shared__ float xs[TM * HD];   // 16 KB
    __shared__ float hs[TM * HD];   // 16 KB
    const int tid = threadIdx.x;
    const long r0 = (long)blockIdx.x * TM;   // first global row (b*S+s)

    // Load 16 rows of X into LDS (coalesced).
    #pragma unroll
    for (int m = 0; m < TM; ++m)
        xs[m * HD + tid] = X[(r0 + m) * HD + tid];
    __syncthreads();

    float acc[TM];

    // ---- Layer 1: hs = relu(xs @ W1 + b1). Thread tid owns output column tid.
    #pragma unroll
    for (int m = 0; m < TM; ++m) acc[m] = 0.f;
    {
        const float4* xs4 = (const float4*)xs;
        for (int h4 = 0; h4 < HD / 4; ++h4) {
            float w0 = W1[(4 * h4 + 0) * HD + tid];
            float w1 = W1[(4 * h4 + 1) * HD + tid];
            float w2 = W1[(4 * h4 + 2) * HD + tid];
            float w3 = W1[(4 * h4 + 3) * HD + tid];
            #pragma unroll
            for (int m = 0; m < TM; ++m) {
                float4 xv = xs4[m * (HD / 4) + h4];   // LDS broadcast b128
                acc[m] = fmaf(xv.x, w0, acc[m]);
                acc[m] = fmaf(xv.y, w1, acc[m]);
                acc[m] = fmaf(xv.z, w2, acc[m]);
                acc[m] = fmaf(xv.w, w3, acc[m]);
            }
        }
    }
    {
        float bias = b1[tid];
        #pragma unroll
        for (int m = 0; m < TM; ++m)
            hs[m * HD + tid] = fmaxf(acc[m] + bias, 0.f);
    }
    __syncthreads();

    // ---- Layer 2: xs = relu(hs @ W2 + b2) (result overwrites xs).
    #pragma unroll
    for (int m = 0; m < TM; ++m) acc[m] = 0.f;
    {
        const float4* hs4 = (const float4*)hs;
        for (int h4 = 0; h4 < HD / 4; ++h4) {
            float w0 = W2[(4 * h4 + 0) * HD + tid];
            float w1 = W2[(4 * h4 + 1) * HD + tid];
            float w2 = W2[(4 * h4 + 2) * HD + tid];
            float w3 = W2[(4 * h4 + 3) * HD + tid];
            #pragma unroll
            for (int m = 0; m < TM; ++m) {
                float4 hv = hs4[m * (HD / 4) + h4];
                acc[m] = fmaf(hv.x, w0, acc[m]);
                acc[m] = fmaf(hv.y, w1, acc[m]);
                acc[m] = fmaf(hv.z, w2, acc[m]);
                acc[m] = fmaf(hv.w, w3, acc[m]);
            }
        }
    }
    {
        float bias = b2[tid];
        #pragma unroll
        for (int m = 0; m < TM; ++m)
            xs[m * HD + tid] = fmaxf(acc[m] + bias, 0.f);
    }
    __syncthreads();

    // ---- Logits: one (m,k) pair per thread. lg stored in hs[0..255].
    {
        int m = tid >> 4, k = tid & 15;
        float d = 0.f;
        for (int h = 0; h < HD; ++h)
            d = fmaf(xs[m * HD + h], W3[h * KD + k], d);
        hs[m * KD + k] = d;
    }
    __syncthreads();

    // ---- Softmax over K, mask, /4. One row per thread (threads 0..15).
    if (tid < TM) {
        int m = tid;
        int mv = mask[r0 + m];
        float mx = -1e30f;
        #pragma unroll
        for (int k = 0; k < KD; ++k) mx = fmaxf(mx, hs[m * KD + k]);
        float e[KD];
        float sum = 0.f;
        #pragma unroll
        for (int k = 0; k < KD; ++k) { e[k] = __expf(hs[m * KD + k] - mx); sum += e[k]; }
        float inv = 1.f / sum;
        #pragma unroll
        for (int k = 0; k < KD; ++k) {
            float p = e[k] * inv;
            hs[m * KD + k] = mv ? p * 0.25f : -2500.0f;   // (-10000)/sqrt(16)
        }
    }
    __syncthreads();

    // Coalesced store: TM*KD == 256 values, one per thread.
    P[r0 * KD + tid] = hs[tid];
}

// ---------------------------------------------------------------------------
// Kernel 2: per-b softmax over S (axis=-2), * time_f_w, then
//           out[b,k,h] = sum_s X[b,s,h] * w[s,k].
// ---------------------------------------------------------------------------
__global__ __launch_bounds__(256) void softs_agg_kernel(
    const float* __restrict__ X, const float* __restrict__ tf,
    const float* __restrict__ P, float* __restrict__ out)
{
    __shared__ float wl[SD * KD];   // 12.8 KB
    __shared__ float tfl[SD];
    const int tid = threadIdx.x;
    const int b = blockIdx.x;

    const float* Pb = P + (long)b * SD * KD;
    for (int i = tid; i < SD * KD; i += 256) wl[i] = Pb[i];
    if (tid < SD) tfl[tid] = tf[b * SD + tid];
    __syncthreads();

    // Column softmax over S for each k (threads 0..15, one k each).
    if (tid < KD) {
        const int k = tid;
        float mx = -1e30f;
        for (int s = 0; s < SD; ++s) mx = fmaxf(mx, wl[s * KD + k]);
        float sum = 0.f;
        for (int s = 0; s < SD; ++s) {
            float e = __expf(wl[s * KD + k] - mx);
            wl[s * KD + k] = e;
            sum += e;
        }
        float inv = 1.f / sum;
        for (int s = 0; s < SD; ++s)
            wl[s * KD + k] = tfl[s] * wl[s * KD + k] * inv;
    }
    __syncthreads();

    // out[b,k,tid] = sum_s X[b,s,tid] * wl[s,k]
    float acc[KD];
    #pragma unroll
    for (int k = 0; k < KD; ++k) acc[k] = 0.f;
    const float* Xb = X + (long)b * SD * HD;
    for (int s = 0; s < SD; ++s) {
        float xv = Xb[s * HD + tid];            // coalesced
        #pragma unroll
        for (int k = 0; k < KD; ++k)
            acc[k] = fmaf(xv, wl[s * KD + k], acc[k]);   // LDS broadcast
    }
    float* ob = out + (long)b * KD * HD;
    #pragma unroll
    for (int k = 0; k < KD; ++k)
        ob[k * HD + tid] = acc[k];
}

extern "C" void kernel_launch(void* const* d_in, const int* in_sizes, int n_in,
                              void* d_out, int out_size, void* d_ws, size_t ws_size,
                              hipStream_t stream) {
    (void)in_sizes; (void)n_in; (void)out_size; (void)ws_size;
    const float* X    = (const float*)d_in[0];   // (B,S,H) f32
    const int*   mask = (const int*)  d_in[1];   // (B,S,1) bool->int
    const float* tf   = (const float*)d_in[2];   // (B,S,1) f32
    const float* W1   = (const float*)d_in[3];   // (H,H)
    const float* b1   = (const float*)d_in[4];   // (H,)
    const float* W2   = (const float*)d_in[5];   // (H,H)
    const float* b2   = (const float*)d_in[6];   // (H,)
    const float* W3   = (const float*)d_in[7];   // (H,K)
    float* out = (float*)d_out;                  // (B,K,H)
    float* P   = (float*)d_ws;                   // (B*S,K) scratch, 6.5 MB

    const int nrows = BD * SD;
    mlp_softk_kernel<<<nrows / TM, 256, 0, stream>>>(X, mask, W1, b1, W2, b2, W3, P);
    softs_agg_kernel<<<BD, 256, 0, stream>>>(X, tf, P, out);
}

// Round 2
// 276.059 us; speedup vs baseline: 2.3964x; 2.3964x over previous
//
#include <hip/hip_runtime.h>
#include <math.h>

#define HDIM 256
#define KDIM 16
#define SDIM 200
#define BDIM 512
#define NROWS (BDIM * SDIM)   // 102400
#define TM 64                 // rows per block in kernel 1

typedef __bf16 bf16x8 __attribute__((ext_vector_type(8)));
typedef __bf16 bf16x4 __attribute__((ext_vector_type(4)));
typedef float  f32x4  __attribute__((ext_vector_type(4)));

// ---------------------------------------------------------------------------
// Pack W (K x N, row-major) into fragment-ready split-bf16 layout:
//   dst[((k>>3)*N + n)*8 + (k&7)] = hi/lo bf16 of W[k*N + n]
// so a lane's B-fragment (8 consecutive k at fixed n) is one 16B load.
// ---------------------------------------------------------------------------
__global__ __launch_bounds__(256) void pack_w_kernel(
    const float* __restrict__ src, __bf16* __restrict__ hi,
    __bf16* __restrict__ lo, int lgN)
{
    int idx = blockIdx.x * 256 + threadIdx.x;
    int N = 1 << lgN;
    int k = idx >> lgN;
    int n = idx & (N - 1);
    float v = src[idx];
    __bf16 h = (__bf16)v;
    float r = v - (float)h;
    int d = (((k >> 3) << lgN) + n) * 8 + (k & 7);
    hi[d] = h;
    lo[d] = (__bf16)r;
}

// ---------------------------------------------------------------------------
// Kernel 1: 64-row tile. Split-bf16 3-pass MFMA for the two 256x256 layers
// and the 256x16 logits, then softmax-K + mask + /4 -> P.
// LDS: A hi/lo, XOR-swizzled k-groups (kg ^ (row&31)) for conflict-free
// ds_read_b128 A-frags. h overwrites the same buffers between layers.
// ---------------------------------------------------------------------------
__global__ __launch_bounds__(256, 2) void mlp_softk_mfma(
    const float* __restrict__ X, const int* __restrict__ mask,
    const __bf16* __restrict__ W1h, const __bf16* __restrict__ W1l,
    const float* __restrict__ b1,
    const __bf16* __restrict__ W2h, const __bf16* __restrict__ W2l,
    const float* __restrict__ b2,
    const __bf16* __restrict__ W3h, const __bf16* __restrict__ W3l,
    float* __restrict__ P)
{
    __shared__ __bf16 Ahi[TM * HDIM];   // 32 KB
    __shared__ __bf16 Alo[TM * HDIM];   // 32 KB

    const int tid  = threadIdx.x;
    const int lane = tid & 63;
    const int w    = tid >> 6;      // wave id: owns cols 64w..64w+63
    const int l15  = lane & 15;
    const int quad = lane >> 4;
    const long r0  = (long)blockIdx.x * TM;

    // ---- stage X tile -> LDS as split bf16 (swizzled) ----
    {
        const float4* Xt = (const float4*)(X + r0 * HDIM);
        #pragma unroll
        for (int t = 0; t < (TM * HDIM / 4) / 256; ++t) {
            int v4  = tid + t * 256;
            float4 f = Xt[v4];
            int row = v4 >> 6;            // 64 float4 per row
            int col = (v4 & 63) << 2;
            int kgs = (col >> 3) ^ (row & 31);
            int base = row * HDIM + kgs * 8 + (col & 7);
            __bf16 h0 = (__bf16)f.x, h1 = (__bf16)f.y,
                   h2 = (__bf16)f.z, h3 = (__bf16)f.w;
            bf16x4 hv = {h0, h1, h2, h3};
            bf16x4 lv = {(__bf16)(f.x - (float)h0), (__bf16)(f.y - (float)h1),
                         (__bf16)(f.z - (float)h2), (__bf16)(f.w - (float)h3)};
            *(bf16x4*)(&Ahi[base]) = hv;
            *(bf16x4*)(&Alo[base]) = lv;
        }
    }
    __syncthreads();

    f32x4 acc[4][4];

    auto layer = [&](const __bf16* __restrict__ Wh, const __bf16* __restrict__ Wl,
                     const float* __restrict__ bias) {
        #pragma unroll
        for (int mt = 0; mt < 4; ++mt)
            #pragma unroll
            for (int nt = 0; nt < 4; ++nt)
                acc[mt][nt] = (f32x4){0.f, 0.f, 0.f, 0.f};

        #pragma unroll 2
        for (int kc = 0; kc < 8; ++kc) {
            bf16x8 ah[4], al[4], bh[4], bl[4];
            #pragma unroll
            for (int mt = 0; mt < 4; ++mt) {
                int row = mt * 16 + l15;
                int kgs = (kc * 4 + quad) ^ (row & 31);
                ah[mt] = *(const bf16x8*)(&Ahi[row * HDIM + kgs * 8]);
                al[mt] = *(const bf16x8*)(&Alo[row * HDIM + kgs * 8]);
            }
            #pragma unroll
            for (int nt = 0; nt < 4; ++nt) {
                int n  = w * 64 + nt * 16 + l15;
                int kg = kc * 4 + quad;
                bh[nt] = *(const bf16x8*)(Wh + (kg * HDIM + n) * 8);
                bl[nt] = *(const bf16x8*)(Wl + (kg * HDIM + n) * 8);
            }
            #pragma unroll
            for (int mt = 0; mt < 4; ++mt)
                #pragma unroll
                for (int nt = 0; nt < 4; ++nt) {
                    acc[mt][nt] = __builtin_amdgcn_mfma_f32_16x16x32_bf16(
                        ah[mt], bh[nt], acc[mt][nt], 0, 0, 0);
                    acc[mt][nt] = __builtin_amdgcn_mfma_f32_16x16x32_bf16(
                        al[mt], bh[nt], acc[mt][nt], 0, 0, 0);
                    acc[mt][nt] = __builtin_amdgcn_mfma_f32_16x16x32_bf16(
                        ah[mt], bl[nt], acc[mt][nt], 0, 0, 0);
                }
        }
        __syncthreads();   // everyone done reading A before overwrite

        float bias_v[4];
        #pragma unroll
        for (int nt = 0; nt < 4; ++nt) bias_v[nt] = bias[w * 64 + nt * 16 + l15];
        #pragma unroll
        for (int mt = 0; mt < 4; ++mt)
            #pragma unroll
            for (int nt = 0; nt < 4; ++nt)
                #pragma unroll
                for (int r = 0; r < 4; ++r) {
                    float v = fmaxf(acc[mt][nt][r] + bias_v[nt], 0.f);
                    int row = mt * 16 + quad * 4 + r;   // C layout: row=(l>>4)*4+reg
                    int col = w * 64 + nt * 16 + l15;   //           col=l&15
                    int idx = row * HDIM + (((col >> 3) ^ (row & 31)) * 8) + (col & 7);
                    __bf16 h = (__bf16)v;
                    Ahi[idx] = h;
                    Alo[idx] = (__bf16)(v - (float)h);
                }
        __syncthreads();
    };

    layer(W1h, W1l, b1);
    layer(W2h, W2l, b2);

    // ---- logits: wave w handles m-tile w (16 rows x 16 k) ----
    f32x4 lg = {0.f, 0.f, 0.f, 0.f};
    #pragma unroll
    for (int kc = 0; kc < 8; ++kc) {
        int row = w * 16 + l15;
        int kg  = kc * 4 + quad;
        int kgs = kg ^ (row & 31);
        bf16x8 ah = *(const bf16x8*)(&Ahi[row * HDIM + kgs * 8]);
        bf16x8 al = *(const bf16x8*)(&Alo[row * HDIM + kgs * 8]);
        bf16x8 bh = *(const bf16x8*)(W3h + (kg * KDIM + l15) * 8);
        bf16x8 bl = *(const bf16x8*)(W3l + (kg * KDIM + l15) * 8);
        lg = __builtin_amdgcn_mfma_f32_16x16x32_bf16(ah, bh, lg, 0, 0, 0);
        lg = __builtin_amdgcn_mfma_f32_16x16x32_bf16(al, bh, lg, 0, 0, 0);
        lg = __builtin_amdgcn_mfma_f32_16x16x32_bf16(ah, bl, lg, 0, 0, 0);
    }

    // ---- softmax over k (16 lanes of a group hold the 16 cols of a row) ----
    #pragma unroll
    for (int r = 0; r < 4; ++r) {
        float v  = lg[r];
        float mx = v;
        mx = fmaxf(mx, __shfl_xor(mx, 1));
        mx = fmaxf(mx, __shfl_xor(mx, 2));
        mx = fmaxf(mx, __shfl_xor(mx, 4));
        mx = fmaxf(mx, __shfl_xor(mx, 8));
        float e = __expf(v - mx);
        float s = e;
        s += __shfl_xor(s, 1);
        s += __shfl_xor(s, 2);
        s += __shfl_xor(s, 4);
        s += __shfl_xor(s, 8);
        int grow = (int)r0 + w * 16 + quad * 4 + r;
        int mv   = mask[grow];
        float ov = mv ? (e / s) * 0.25f : -2500.0f;   // (-10000)/sqrt(16)
        P[(long)grow * KDIM + l15] = ov;
    }
}

// ---------------------------------------------------------------------------
// Kernel 2: per-b softmax over S (no max-sub needed: logits <= 0.25 or -2500),
// * time_f_w, then out[b,k,h] = sum_s X[b,s,h] * D[s,k].
// Wave w owns k = 4w..4w+3 over all s; float4 X loads (L1/L2 absorb the 4x
// intra-block re-read).
// ---------------------------------------------------------------------------
__global__ __launch_bounds__(256, 2) void softs_agg_kernel(
    const float* __restrict__ X, const float* __restrict__ tf,
    const float* __restrict__ P, float* __restrict__ out)
{
    __shared__ float wl[SDIM * KDIM];   // 12.8 KB
    __shared__ float tfl[SDIM];
    __shared__ float psum[256];
    __shared__ float invk[KDIM];

    const int tid = threadIdx.x;
    const int b   = blockIdx.x;

    const float* Pb = P + (long)b * SDIM * KDIM;
    float ps = 0.f;
    #pragma unroll
    for (int t = 0; t < 13; ++t) {
        int i = tid + t * 256;
        if (i < SDIM * KDIM) {
            float e = __expf(Pb[i]);   // exp(-2500) == 0 handles the mask
            wl[i] = e;
            ps += e;
        }
    }
    psum[tid] = ps;
    if (tid < SDIM) tfl[tid] = tf[b * SDIM + tid];
    __syncthreads();

    if (tid < KDIM) {
        float s = 0.f;
        #pragma unroll
        for (int g = 0; g < 16; ++g) s += psum[tid + g * 16];
        invk[tid] = 1.f / s;
    }
    __syncthreads();

    #pragma unroll
    for (int t = 0; t < 13; ++t) {
        int i = tid + t * 256;
        if (i < SDIM * KDIM) wl[i] *= tfl[i >> 4] * invk[i & 15];
    }
    __syncthreads();

    const int w  = tid >> 6;    // wave -> k group 4w..4w+3
    const int ln = tid & 63;    // lane -> cols 4ln..4ln+3
    f32x4 acc[4];
    #pragma unroll
    for (int j = 0; j < 4; ++j) acc[j] = (f32x4){0.f, 0.f, 0.f, 0.f};

    const float4* Xb = (const float4*)(X + (long)b * SDIM * HDIM);
    for (int s = 0; s < SDIM; ++s) {
        float4 xv = Xb[s * 64 + ln];
        f32x4 x = {xv.x, xv.y, xv.z, xv.w};
        #pragma unroll
        for (int j = 0; j < 4; ++j) {
            float wt = wl[s * KDIM + 4 * w + j];
            acc[j] += x * wt;
        }
    }

    float4* Ob = (float4*)(out + (long)b * KDIM * HDIM);
    #pragma unroll
    for (int j = 0; j < 4; ++j) {
        float4 o = {acc[j][0], acc[j][1], acc[j][2], acc[j][3]};
        Ob[(4 * w + j) * 64 + ln] = o;
    }
}

extern "C" void kernel_launch(void* const* d_in, const int* in_sizes, int n_in,
                              void* d_out, int out_size, void* d_ws, size_t ws_size,
                              hipStream_t stream) {
    (void)in_sizes; (void)n_in; (void)out_size; (void)ws_size;
    const float* X    = (const float*)d_in[0];
    const int*   mask = (const int*)  d_in[1];
    const float* tf   = (const float*)d_in[2];
    const float* W1   = (const float*)d_in[3];
    const float* b1   = (const float*)d_in[4];
    const float* W2   = (const float*)d_in[5];
    const float* b2   = (const float*)d_in[6];
    const float* W3   = (const float*)d_in[7];
    float* out = (float*)d_out;

    char* ws = (char*)d_ws;
    float*  P   = (float*)ws;                          // 102400*16*4 = 6,553,600 B
    __bf16* w1h = (__bf16*)(ws + 6553600);             // 65536 elems each
    __bf16* w1l = w1h + 65536;
    __bf16* w2h = w1l + 65536;
    __bf16* w2l = w2h + 65536;
    __bf16* w3h = w2l + 65536;                         // 4096 elems each
    __bf16* w3l = w3h + 4096;

    pack_w_kernel<<<256, 256, 0, stream>>>(W1, w1h, w1l, 8);
    pack_w_kernel<<<256, 256, 0, stream>>>(W2, w2h, w2l, 8);
    pack_w_kernel<<<16,  256, 0, stream>>>(W3, w3h, w3l, 4);
    mlp_softk_mfma<<<NROWS / TM, 256, 0, stream>>>(X, mask, w1h, w1l, b1,
                                                   w2h, w2l, b2, w3h, w3l, P);
    softs_agg_kernel<<<BDIM, 256, 0, stream>>>(X, tf, P, out);
}